// Round 2
// baseline (1314.298 us; speedup 1.0000x reference)
//
#include <hip/hip_runtime.h>

#define NN 16384
#define FF 2000
#define HH 128
#define LL 15
constexpr float BN_EPS = 1e-3f;

// ---------------- CSR build: histogram ----------------
__global__ void hist_kernel(const int* __restrict__ dm_row, const int* __restrict__ knn_row,
                            int* __restrict__ cnt_dm, int* __restrict__ cnt_knn, int E) {
  int i = blockIdx.x * 256 + threadIdx.x;
  if (i < E) atomicAdd(&cnt_dm[dm_row[i]], 1);
  else if (i - E < E) atomicAdd(&cnt_knn[knn_row[i - E]], 1);
}

// ---------------- CSR build: exclusive scan (simple & obviously correct) ----------------
__global__ void scan_kernel(const int* __restrict__ cnt0, int* __restrict__ rp0, int* __restrict__ off0,
                            const int* __restrict__ cnt1, int* __restrict__ rp1, int* __restrict__ off1) {
  const int* cnt = blockIdx.x ? cnt1 : cnt0;
  int* rp  = blockIdx.x ? rp1 : rp0;
  int* off = blockIdx.x ? off1 : off0;
  __shared__ int part[256];
  __shared__ int totsh;
  int t = threadIdx.x;
  int s = 0;
  for (int i = 0; i < 64; ++i) s += cnt[t * 64 + i];
  part[t] = s;
  __syncthreads();
  if (t == 0) {
    int run = 0;
    for (int i = 0; i < 256; ++i) { int c = part[i]; part[i] = run; run += c; }
    totsh = run;
  }
  __syncthreads();
  int base = part[t];
  for (int i = 0; i < 64; ++i) {
    int idx = t * 64 + i;
    rp[idx] = base;
    off[idx] = base;
    base += cnt[idx];
  }
  if (t == 0) rp[NN] = totsh;
}

// ---------------- CSR build: scatter ----------------
__global__ void scatter_kernel(const int* __restrict__ dm_row, const int* __restrict__ dm_col, const float* __restrict__ dm_w,
                               const int* __restrict__ knn_row, const int* __restrict__ knn_col, const float* __restrict__ knn_w,
                               int* __restrict__ off_dm, int* __restrict__ cs_dm, float* __restrict__ wv_dm,
                               int* __restrict__ off_knn, int* __restrict__ cs_knn, float* __restrict__ wv_knn, int E) {
  int i = blockIdx.x * 256 + threadIdx.x;
  if (i < E) {
    int r = dm_row[i];
    int p = atomicAdd(&off_dm[r], 1);
    cs_dm[p] = dm_col[i];
    wv_dm[p] = dm_w[i];
  } else if (i - E < E) {
    int j = i - E;
    int r = knn_row[j];
    int p = atomicAdd(&off_knn[r], 1);
    cs_knn[p] = knn_col[j];
    wv_knn[p] = knn_w[j];
  }
}

// ---------------- GEMM1 (per branch): Yb[N x 384] = X[N x 2000] @ W1 parts ----------------
// blockIdx.x = part p (0..2): Yb[:, p*128 : p*128+128] = X @ W1[p*FF : p*FF+FF, :]
__global__ __launch_bounds__(256) void gemm1_kernel(const float* __restrict__ X,
                                                    const float* __restrict__ W1,
                                                    float* __restrict__ Yb) {
  __shared__ float As[8][128];  // [k][m]
  __shared__ float Bs[8][128];  // [k][n]
  int t = threadIdx.x;
  int tx = t & 15, ty = t >> 4;
  int p = blockIdx.x;
  int n0 = p * 128;
  int m0 = blockIdx.y * 128;
  int arow = t >> 1, akoff = (t & 1) * 4;
  int brow = t >> 5, bcol = (t & 31) * 4;
  const float* Xp = X + (size_t)(m0 + arow) * FF + akoff;
  const float* Wp = W1 + ((size_t)p * FF + brow) * HH + bcol;
  float acc[2][2][4][4] = {};
  for (int k0 = 0; k0 < FF; k0 += 8) {
    float4 av = *(const float4*)(Xp + k0);
    float4 bv = *(const float4*)(Wp + (size_t)k0 * HH);
    __syncthreads();
    As[akoff + 0][arow] = av.x;
    As[akoff + 1][arow] = av.y;
    As[akoff + 2][arow] = av.z;
    As[akoff + 3][arow] = av.w;
    *(float4*)&Bs[brow][bcol] = bv;
    __syncthreads();
#pragma unroll
    for (int k = 0; k < 8; ++k) {
      float4 a0 = *(const float4*)&As[k][ty * 4];
      float4 a1 = *(const float4*)&As[k][64 + ty * 4];
      float4 b0 = *(const float4*)&Bs[k][tx * 4];
      float4 b1 = *(const float4*)&Bs[k][64 + tx * 4];
      float ar[2][4] = {{a0.x, a0.y, a0.z, a0.w}, {a1.x, a1.y, a1.z, a1.w}};
      float br[2][4] = {{b0.x, b0.y, b0.z, b0.w}, {b1.x, b1.y, b1.z, b1.w}};
#pragma unroll
      for (int i2 = 0; i2 < 2; ++i2)
#pragma unroll
        for (int j2 = 0; j2 < 2; ++j2)
#pragma unroll
          for (int r = 0; r < 4; ++r)
#pragma unroll
            for (int c = 0; c < 4; ++c)
              acc[i2][j2][r][c] = fmaf(ar[i2][r], br[j2][c], acc[i2][j2][r][c]);
    }
  }
#pragma unroll
  for (int i2 = 0; i2 < 2; ++i2)
#pragma unroll
    for (int r = 0; r < 4; ++r) {
      int row = m0 + i2 * 64 + ty * 4 + r;
      float* yr = Yb + (size_t)row * 384 + n0;
#pragma unroll
      for (int j2 = 0; j2 < 2; ++j2) {
        float4 vv;
        vv.x = acc[i2][j2][r][0];
        vv.y = acc[i2][j2][r][1];
        vv.z = acc[i2][j2][r][2];
        vv.w = acc[i2][j2][r][3];
        *(float4*)(yr + j2 * 64 + tx * 4) = vv;
      }
    }
}

// ---------------- spmm width 128: dst[row][0:128] = sum_e w*src[col] (+ addv[row]) ----------------
__global__ void spmm128_kernel(const int* __restrict__ rp, const int* __restrict__ cs, const float* __restrict__ wv,
                               const float* __restrict__ src, int sstr,
                               const float* __restrict__ addv, int astr,
                               float* __restrict__ dst) {
  int row = blockIdx.x * 4 + (threadIdx.x >> 6);
  int lane = threadIdx.x & 63;
  int e0 = rp[row], e1 = rp[row + 1];
  float ax = 0.f, ay = 0.f;
  int e = e0;
  for (; e + 3 < e1; e += 4) {
    int c0 = cs[e], c1 = cs[e + 1], c2 = cs[e + 2], c3 = cs[e + 3];
    float w0 = wv[e], w1 = wv[e + 1], w2 = wv[e + 2], w3 = wv[e + 3];
    float2 v0 = *(const float2*)(src + (size_t)c0 * sstr + 2 * lane);
    float2 v1 = *(const float2*)(src + (size_t)c1 * sstr + 2 * lane);
    float2 v2 = *(const float2*)(src + (size_t)c2 * sstr + 2 * lane);
    float2 v3 = *(const float2*)(src + (size_t)c3 * sstr + 2 * lane);
    ax = fmaf(w0, v0.x, ax); ay = fmaf(w0, v0.y, ay);
    ax = fmaf(w1, v1.x, ax); ay = fmaf(w1, v1.y, ay);
    ax = fmaf(w2, v2.x, ax); ay = fmaf(w2, v2.y, ay);
    ax = fmaf(w3, v3.x, ax); ay = fmaf(w3, v3.y, ay);
  }
  for (; e < e1; ++e) {
    int c = cs[e];
    float wgt = wv[e];
    float2 v = *(const float2*)(src + (size_t)c * sstr + 2 * lane);
    ax = fmaf(wgt, v.x, ax);
    ay = fmaf(wgt, v.y, ay);
  }
  if (addv) {
    ax += addv[(size_t)row * astr + 2 * lane];
    ay += addv[(size_t)row * astr + 2 * lane + 1];
  }
  *(float2*)(dst + (size_t)row * HH + 2 * lane) = make_float2(ax, ay);
}

// ---------------- BN + ReLU: H = relu(bn(Y0 + T2 + b1)) ----------------
__global__ void bnrelu_kernel(const float* __restrict__ Y0, int ystr, const float* __restrict__ T2,
                              const float* __restrict__ b1, const float* __restrict__ g,
                              const float* __restrict__ be, const float* __restrict__ m,
                              const float* __restrict__ v, float* __restrict__ H) {
  int i = blockIdx.x * 256 + threadIdx.x;
  int row = i >> 7, h = i & 127;
  float tv = Y0[(size_t)row * ystr + h] + T2[i] + b1[h];
  float yv = g[h] * (tv - m[h]) * rsqrtf(v[h] + BN_EPS) + be[h];
  H[i] = fmaxf(yv, 0.f);
}

// ---------------- GEMM2: P[N x 45] = H[N x 128] @ [V0|V1|V2] ----------------
__global__ void gemm2_kernel(const float* __restrict__ H, const float* __restrict__ W2,
                             float* __restrict__ P) {
  __shared__ float V[128 * 48];
  int t = threadIdx.x;
  for (int idx = t; idx < 128 * 48; idx += 256) {
    int k = idx / 48, j = idx % 48;
    float val = 0.f;
    if (j < 45) {
      int p = j / 15, l = j % 15;
      val = W2[(size_t)(p * 128 + k) * 15 + l];
    }
    V[idx] = val;
  }
  __syncthreads();
  int rq = t >> 4, l = t & 15;
  int row = blockIdx.x * 16 + rq;
  float a0 = 0.f, a1 = 0.f, a2 = 0.f;
  const float* hrow = H + (size_t)row * 128;
  for (int k = 0; k < 128; ++k) {
    float hv = hrow[k];
    a0 = fmaf(hv, V[k * 48 + l], a0);
    a1 = fmaf(hv, V[k * 48 + 16 + l], a1);
    a2 = fmaf(hv, V[k * 48 + 32 + l], a2);
  }
  float* pr = P + (size_t)row * 45;
  pr[l] = a0;
  pr[16 + l] = a1;
  if (l < 13) pr[32 + l] = a2;
}

// ---------------- spmm width 15 (16 lanes per row) ----------------
__global__ void spmm15_kernel(const int* __restrict__ rp, const int* __restrict__ cs, const float* __restrict__ wv,
                              const float* __restrict__ src, int sstr, int soff,
                              const float* __restrict__ addv, int astr, int aoff,
                              const float* __restrict__ bias,
                              float* __restrict__ dst, int dstr, int accum) {
  int t = threadIdx.x;
  int rq = t >> 4, f = t & 15;
  int row = blockIdx.x * 16 + rq;
  int e0 = rp[row], e1 = rp[row + 1];
  bool valid = f < 15;
  int ff = valid ? f : 0;
  float acc = 0.f;
  for (int e = e0; e < e1; ++e) {
    int c = cs[e];
    float wgt = wv[e];
    acc = fmaf(wgt, src[(size_t)c * sstr + soff + ff], acc);
  }
  if (addv) acc += addv[(size_t)row * astr + aoff + ff];
  if (bias) acc += bias[ff];
  if (valid) {
    float* d = dst + (size_t)row * dstr + f;
    if (accum) *d += acc;
    else *d = acc;
  }
}

extern "C" void kernel_launch(void* const* d_in, const int* in_sizes, int n_in,
                              void* d_out, int out_size, void* d_ws, size_t ws_size,
                              hipStream_t stream) {
  const float* x      = (const float*)d_in[0];
  const int* dm_row   = (const int*)d_in[1];
  const int* dm_col   = (const int*)d_in[2];
  const float* dm_w   = (const float*)d_in[3];
  const int* knn_row  = (const int*)d_in[4];
  const int* knn_col  = (const int*)d_in[5];
  const float* knn_w  = (const float*)d_in[6];
  const float* W_dm1  = (const float*)d_in[7];
  const float* b_dm1  = (const float*)d_in[8];
  const float* g_dm   = (const float*)d_in[9];
  const float* be_dm  = (const float*)d_in[10];
  const float* m_dm   = (const float*)d_in[11];
  const float* v_dm   = (const float*)d_in[12];
  const float* W_dm2  = (const float*)d_in[13];
  const float* b_dm2  = (const float*)d_in[14];
  const float* W_knn1 = (const float*)d_in[15];
  const float* b_knn1 = (const float*)d_in[16];
  const float* g_knn  = (const float*)d_in[17];
  const float* be_knn = (const float*)d_in[18];
  const float* m_knn  = (const float*)d_in[19];
  const float* v_knn  = (const float*)d_in[20];
  const float* W_knn2 = (const float*)d_in[21];
  const float* b_knn2 = (const float*)d_in[22];
  float* out = (float*)d_out;

  const int E = in_sizes[1];  // edge count (reference: 524288)

  // ---- compact workspace layout (~51 MB peak) with reuse ----
  float* wbase = (float*)d_ws;
  size_t o = 0;
  auto alloc = [&](size_t n) { float* p = wbase + o; o += (n + 3) & ~size_t(3); return p; };
  int* cnt_dm   = (int*)alloc(NN);
  int* cnt_knn  = (int*)alloc(NN);
  int* rp_dm    = (int*)alloc(NN + 1);
  int* off_dm   = (int*)alloc(NN);
  int* rp_knn   = (int*)alloc(NN + 1);
  int* off_knn  = (int*)alloc(NN);
  int* cs_dm    = (int*)alloc(E);
  float* wv_dm  = alloc(E);
  int* cs_knn   = (int*)alloc(E);
  float* wv_knn = alloc(E);
  float* Yb  = alloc((size_t)NN * 384);   // per-branch [x@W0 | x@W1 | x@W2]
  float* T1  = alloc((size_t)NN * HH);
  float* T2c = alloc((size_t)NN * HH);
  float* Hb  = T1;    // reuse: T1 dead once T2c computed
  float* Pb  = T2c;   // reuse: T2c dead once Hb computed (N*45 < N*128)
  float* T15 = Yb;    // reuse: Yb dead once Hb computed (N*15 < N*384)

  hipMemsetAsync(cnt_dm, 0, 2 * NN * sizeof(int), stream);
  int nb2e = (2 * E + 255) / 256;
  hist_kernel<<<nb2e, 256, 0, stream>>>(dm_row, knn_row, cnt_dm, cnt_knn, E);
  scan_kernel<<<2, 256, 0, stream>>>(cnt_dm, rp_dm, off_dm, cnt_knn, rp_knn, off_knn);
  scatter_kernel<<<nb2e, 256, 0, stream>>>(dm_row, dm_col, dm_w, knn_row, knn_col, knn_w,
                                           off_dm, cs_dm, wv_dm, off_knn, cs_knn, wv_knn, E);

  for (int b = 0; b < 2; ++b) {
    const int* rp   = b ? rp_knn : rp_dm;
    const int* cs   = b ? cs_knn : cs_dm;
    const float* wv = b ? wv_knn : wv_dm;
    const float* W1 = b ? W_knn1 : W_dm1;
    const float* W2 = b ? W_knn2 : W_dm2;
    const float* b1 = b ? b_knn1 : b_dm1;
    const float* b2 = b ? b_knn2 : b_dm2;
    const float* g  = b ? g_knn : g_dm;
    const float* be = b ? be_knn : be_dm;
    const float* mm = b ? m_knn : m_dm;
    const float* vv = b ? v_knn : v_dm;

    // Yb = [x@W0 | x@W1 | x@W2]
    gemm1_kernel<<<dim3(3, NN / 128), 256, 0, stream>>>(x, W1, Yb);
    // T1 = A*(x@W2) + (x@W1)
    spmm128_kernel<<<NN / 4, 256, 0, stream>>>(rp, cs, wv, Yb + 256, 384, Yb + 128, 384, T1);
    // T2 = A*T1
    spmm128_kernel<<<NN / 4, 256, 0, stream>>>(rp, cs, wv, T1, HH, nullptr, 0, T2c);
    // H = relu(bn(Y0 + T2 + b1))   (writes into T1's buffer; reads Yb, T2c only)
    bnrelu_kernel<<<(NN * HH) / 256, 256, 0, stream>>>(Yb, 384, T2c, b1, g, be, mm, vv, Hb);
    // P = H @ [V0|V1|V2]           (writes into T2c's buffer; reads Hb only)
    gemm2_kernel<<<NN / 16, 256, 0, stream>>>(Hb, W2, Pb);
    // T15 = A*P2 + P1              (writes into Yb's buffer; reads Pb only)
    spmm15_kernel<<<NN / 16, 256, 0, stream>>>(rp, cs, wv, Pb, 45, 30, Pb, 45, 15, nullptr, T15, 15, 0);
    // out (=/+=) A*T15 + P0 + b2
    spmm15_kernel<<<NN / 16, 256, 0, stream>>>(rp, cs, wv, T15, 15, 0, Pb, 45, 0, b2, out, 15, b);
  }
}

// Round 8
// 838.634 us; speedup vs baseline: 1.5672x; 1.5672x over previous
//
#include <hip/hip_runtime.h>

#define NN 16384
#define FF 2000
#define HH 128
#define LL 15
#define KP 2016   // 63 * 32, zero-padded K
constexpr float BN_EPS = 1e-3f;

typedef _Float16 half8 __attribute__((ext_vector_type(8)));
typedef __fp16 fp16x2 __attribute__((ext_vector_type(2)));
typedef float f32x4 __attribute__((ext_vector_type(4)));

// ---------------- CSR build: histogram ----------------
__global__ void hist_kernel(const int* __restrict__ dm_row, const int* __restrict__ knn_row,
                            int* __restrict__ cnt_dm, int* __restrict__ cnt_knn, int E) {
  int i = blockIdx.x * 256 + threadIdx.x;
  if (i < E) atomicAdd(&cnt_dm[dm_row[i]], 1);
  else if (i - E < E) atomicAdd(&cnt_knn[knn_row[i - E]], 1);
}

// ---------------- CSR build: exclusive scan ----------------
__global__ void scan_kernel(const int* __restrict__ cnt0, int* __restrict__ rp0, int* __restrict__ off0,
                            const int* __restrict__ cnt1, int* __restrict__ rp1, int* __restrict__ off1) {
  const int* cnt = blockIdx.x ? cnt1 : cnt0;
  int* rp  = blockIdx.x ? rp1 : rp0;
  int* off = blockIdx.x ? off1 : off0;
  __shared__ int part[256];
  __shared__ int totsh;
  int t = threadIdx.x;
  int s = 0;
  for (int i = 0; i < 64; ++i) s += cnt[t * 64 + i];
  part[t] = s;
  __syncthreads();
  if (t == 0) {
    int run = 0;
    for (int i = 0; i < 256; ++i) { int c = part[i]; part[i] = run; run += c; }
    totsh = run;
  }
  __syncthreads();
  int base = part[t];
  for (int i = 0; i < 64; ++i) {
    int idx = t * 64 + i;
    rp[idx] = base;
    off[idx] = base;
    base += cnt[idx];
  }
  if (t == 0) rp[NN] = totsh;
}

// ---------------- CSR build: scatter ----------------
__global__ void scatter_kernel(const int* __restrict__ dm_row, const int* __restrict__ dm_col, const float* __restrict__ dm_w,
                               const int* __restrict__ knn_row, const int* __restrict__ knn_col, const float* __restrict__ knn_w,
                               int* __restrict__ off_dm, int* __restrict__ cs_dm, float* __restrict__ wv_dm,
                               int* __restrict__ off_knn, int* __restrict__ cs_knn, float* __restrict__ wv_knn, int E) {
  int i = blockIdx.x * 256 + threadIdx.x;
  if (i < E) {
    int r = dm_row[i];
    int p = atomicAdd(&off_dm[r], 1);
    cs_dm[p] = dm_col[i];
    wv_dm[p] = dm_w[i];
  } else if (i - E < E) {
    int j = i - E;
    int r = knn_row[j];
    int p = atomicAdd(&off_knn[r], 1);
    cs_knn[p] = knn_col[j];
    wv_knn[p] = knn_w[j];
  }
}

// ---------------- WT build: WT[j][k] fp16, j in [0,384), k in [0,2016) ----------------
// j = p*128 + h ; source W1[(p*2000 + k)*128 + h] ; zero-pad k >= 2000
__global__ void build_wt(const float* __restrict__ W1, _Float16* __restrict__ WT) {
  int idx = blockIdx.x * 256 + threadIdx.x;
  if (idx >= 384 * KP) return;
  int j = idx / KP, k = idx - j * KP;
  float v = 0.f;
  if (k < FF) {
    int p = j >> 7, h = j & 127;
    v = W1[((size_t)p * FF + k) * HH + h];
  }
  WT[idx] = (_Float16)v;
}

// ---------------- GEMM1 MFMA: Yb[16384 x 384] = X[16384 x 2000] @ W (fp16 inputs, fp32 acc) ----
__global__ __launch_bounds__(256, 1) void gemm1_mfma(const float* __restrict__ X,
                                                     const _Float16* __restrict__ WT,
                                                     float* __restrict__ Yb) {
  __shared__ ushort Asm[2][128 * 32];  // [buf][row*32 + k] fp16 bits, XOR-swizzled 16B chunks
  __shared__ ushort Bsm[2][128 * 32];  // same geometry, rows = n-cols of W

  const int t = threadIdx.x;
  const int n0 = blockIdx.x * 128;   // 0,128,256
  const int m0 = blockIdx.y * 128;
  const int wid = t >> 6, lane = t & 63;
  const int wr = wid >> 1, wc = wid & 1;
  const int l15 = lane & 15, lk = lane >> 4;

  // staging coords: thread covers row srow, k-segment of 16
  const int srow = t >> 1;
  const int skseg = (t & 1) << 4;
  const int swz = (srow & 7) << 4;
  const int a_w0 = (srow * 64 + skseg * 2) ^ swz;
  const int a_w1 = (srow * 64 + skseg * 2 + 16) ^ swz;

  const float* Xp = X + (size_t)(m0 + srow) * FF;
  const _Float16* Wp = WT + (size_t)(n0 + srow) * KP;

  // fragment read byte-offsets
  int a_r[4], b_r[4];
#pragma unroll
  for (int i = 0; i < 4; ++i) {
    int row = wr * 64 + i * 16 + l15;
    a_r[i] = (row * 64 + lk * 16) ^ ((row & 7) << 4);
    int nr = wc * 64 + i * 16 + l15;
    b_r[i] = (nr * 64 + lk * 16) ^ ((nr & 7) << 4);
  }

  struct Sreg { float4 a[4]; uint4 b[2]; };
  Sreg S0, S1;

  auto LOADS = [&](Sreg& S, int T) {
    int k0n = T * 32;
    int k0c = (k0n < 1984) ? k0n : 1984;   // clamp keeps addresses in-bounds
    bool aval = (k0n + skseg) < FF;        // 16-aligned segment fully valid or fully pad
    const float* Xq = Xp + k0c + skseg;
    float4 fz = make_float4(0.f, 0.f, 0.f, 0.f);
#pragma unroll
    for (int q = 0; q < 4; ++q)
      S.a[q] = aval ? *(const float4*)(Xq + q * 4) : fz;
    const _Float16* Wq = Wp + k0c + skseg;
    S.b[0] = *(const uint4*)(Wq);
    S.b[1] = *(const uint4*)(Wq + 8);
  };

  auto STAGE = [&](const Sreg& S, char* ab, char* bb) {
    unsigned int u[8];
#pragma unroll
    for (int q = 0; q < 4; ++q) {
      fp16x2 h0 = __builtin_amdgcn_cvt_pkrtz(S.a[q].x, S.a[q].y);
      fp16x2 h1 = __builtin_amdgcn_cvt_pkrtz(S.a[q].z, S.a[q].w);
      u[2 * q]     = __builtin_bit_cast(unsigned int, h0);
      u[2 * q + 1] = __builtin_bit_cast(unsigned int, h1);
    }
    *(uint4*)(ab + a_w0) = make_uint4(u[0], u[1], u[2], u[3]);
    *(uint4*)(ab + a_w1) = make_uint4(u[4], u[5], u[6], u[7]);
    *(uint4*)(bb + a_w0) = S.b[0];
    *(uint4*)(bb + a_w1) = S.b[1];
  };

  f32x4 acc[4][4];
#pragma unroll
  for (int i = 0; i < 4; ++i)
#pragma unroll
    for (int j = 0; j < 4; ++j) acc[i][j] = (f32x4)0.f;

  // prologue: step0 -> buf0 ; preload step1
  LOADS(S0, 0);
  STAGE(S0, (char*)Asm[0], (char*)Bsm[0]);
  LOADS(S1, 1);

#define GITER(Texp, Scons, Sload, CUR)                                              \
  do {                                                                              \
    __syncthreads();                                                                \
    half8 af[4], bf[4];                                                             \
    _Pragma("unroll") for (int i = 0; i < 4; ++i)                                   \
        af[i] = *(const half8*)((const char*)Asm[CUR] + a_r[i]);                    \
    _Pragma("unroll") for (int j = 0; j < 4; ++j)                                   \
        bf[j] = *(const half8*)((const char*)Bsm[CUR] + b_r[j]);                    \
    LOADS(Sload, (Texp) + 2);                                                       \
    _Pragma("unroll") for (int i = 0; i < 4; ++i)                                   \
      _Pragma("unroll") for (int j = 0; j < 4; ++j)                                 \
        acc[i][j] = __builtin_amdgcn_mfma_f32_16x16x32_f16(af[i], bf[j],            \
                                                           acc[i][j], 0, 0, 0);    \
    STAGE(Scons, (char*)Asm[(CUR) ^ 1], (char*)Bsm[(CUR) ^ 1]);                     \
  } while (0)

  for (int tp = 0; tp < 31; ++tp) {
    GITER(2 * tp, S1, S0, 0);
    GITER(2 * tp + 1, S0, S1, 1);
  }
  GITER(62, S1, S0, 0);
#undef GITER

  // epilogue: C/D layout col=lane&15, row=(lane>>4)*4+reg
#pragma unroll
  for (int i = 0; i < 4; ++i) {
#pragma unroll
    for (int j = 0; j < 4; ++j) {
      int row = m0 + wr * 64 + i * 16 + lk * 4;
      int col = n0 + wc * 64 + j * 16 + l15;
#pragma unroll
      for (int r = 0; r < 4; ++r)
        Yb[(size_t)(row + r) * 384 + col] = acc[i][j][r];
    }
  }
}

// ---------------- spmm width 128 ----------------
__global__ void spmm128_kernel(const int* __restrict__ rp, const int* __restrict__ cs, const float* __restrict__ wv,
                               const float* __restrict__ src, int sstr,
                               const float* __restrict__ addv, int astr,
                               float* __restrict__ dst) {
  int row = blockIdx.x * 4 + (threadIdx.x >> 6);
  int lane = threadIdx.x & 63;
  int e0 = rp[row], e1 = rp[row + 1];
  float ax = 0.f, ay = 0.f;
  int e = e0;
  for (; e + 3 < e1; e += 4) {
    int c0 = cs[e], c1 = cs[e + 1], c2 = cs[e + 2], c3 = cs[e + 3];
    float w0 = wv[e], w1 = wv[e + 1], w2 = wv[e + 2], w3 = wv[e + 3];
    float2 v0 = *(const float2*)(src + (size_t)c0 * sstr + 2 * lane);
    float2 v1 = *(const float2*)(src + (size_t)c1 * sstr + 2 * lane);
    float2 v2 = *(const float2*)(src + (size_t)c2 * sstr + 2 * lane);
    float2 v3 = *(const float2*)(src + (size_t)c3 * sstr + 2 * lane);
    ax = fmaf(w0, v0.x, ax); ay = fmaf(w0, v0.y, ay);
    ax = fmaf(w1, v1.x, ax); ay = fmaf(w1, v1.y, ay);
    ax = fmaf(w2, v2.x, ax); ay = fmaf(w2, v2.y, ay);
    ax = fmaf(w3, v3.x, ax); ay = fmaf(w3, v3.y, ay);
  }
  for (; e < e1; ++e) {
    int c = cs[e];
    float wgt = wv[e];
    float2 v = *(const float2*)(src + (size_t)c * sstr + 2 * lane);
    ax = fmaf(wgt, v.x, ax);
    ay = fmaf(wgt, v.y, ay);
  }
  if (addv) {
    ax += addv[(size_t)row * astr + 2 * lane];
    ay += addv[(size_t)row * astr + 2 * lane + 1];
  }
  *(float2*)(dst + (size_t)row * HH + 2 * lane) = make_float2(ax, ay);
}

// ---------------- BN + ReLU ----------------
__global__ void bnrelu_kernel(const float* __restrict__ Y0, int ystr, const float* __restrict__ T2,
                              const float* __restrict__ b1, const float* __restrict__ g,
                              const float* __restrict__ be, const float* __restrict__ m,
                              const float* __restrict__ v, float* __restrict__ H) {
  int i = blockIdx.x * 256 + threadIdx.x;
  int row = i >> 7, h = i & 127;
  float tv = Y0[(size_t)row * ystr + h] + T2[i] + b1[h];
  float yv = g[h] * (tv - m[h]) * rsqrtf(v[h] + BN_EPS) + be[h];
  H[i] = fmaxf(yv, 0.f);
}

// ---------------- GEMM2: P[N x 45] = H[N x 128] @ [V0|V1|V2] ----------------
__global__ void gemm2_kernel(const float* __restrict__ H, const float* __restrict__ W2,
                             float* __restrict__ P) {
  __shared__ float V[128 * 48];
  int t = threadIdx.x;
  for (int idx = t; idx < 128 * 48; idx += 256) {
    int k = idx / 48, j = idx % 48;
    float val = 0.f;
    if (j < 45) {
      int p = j / 15, l = j % 15;
      val = W2[(size_t)(p * 128 + k) * 15 + l];
    }
    V[idx] = val;
  }
  __syncthreads();
  int rq = t >> 4, l = t & 15;
  int row = blockIdx.x * 16 + rq;
  float a0 = 0.f, a1 = 0.f, a2 = 0.f;
  const float* hrow = H + (size_t)row * 128;
  for (int k = 0; k < 128; ++k) {
    float hv = hrow[k];
    a0 = fmaf(hv, V[k * 48 + l], a0);
    a1 = fmaf(hv, V[k * 48 + 16 + l], a1);
    a2 = fmaf(hv, V[k * 48 + 32 + l], a2);
  }
  float* pr = P + (size_t)row * 45;
  pr[l] = a0;
  pr[16 + l] = a1;
  if (l < 13) pr[32 + l] = a2;
}

// ---------------- spmm width 15 (16 lanes per row) ----------------
__global__ void spmm15_kernel(const int* __restrict__ rp, const int* __restrict__ cs, const float* __restrict__ wv,
                              const float* __restrict__ src, int sstr, int soff,
                              const float* __restrict__ addv, int astr, int aoff,
                              const float* __restrict__ bias,
                              float* __restrict__ dst, int dstr, int accum) {
  int t = threadIdx.x;
  int rq = t >> 4, f = t & 15;
  int row = blockIdx.x * 16 + rq;
  int e0 = rp[row], e1 = rp[row + 1];
  bool valid = f < 15;
  int ff = valid ? f : 0;
  float acc = 0.f;
  for (int e = e0; e < e1; ++e) {
    int c = cs[e];
    float wgt = wv[e];
    acc = fmaf(wgt, src[(size_t)c * sstr + soff + ff], acc);
  }
  if (addv) acc += addv[(size_t)row * astr + aoff + ff];
  if (bias) acc += bias[ff];
  if (valid) {
    float* d = dst + (size_t)row * dstr + f;
    if (accum) *d += acc;
    else *d = acc;
  }
}

extern "C" void kernel_launch(void* const* d_in, const int* in_sizes, int n_in,
                              void* d_out, int out_size, void* d_ws, size_t ws_size,
                              hipStream_t stream) {
  const float* x      = (const float*)d_in[0];
  const int* dm_row   = (const int*)d_in[1];
  const int* dm_col   = (const int*)d_in[2];
  const float* dm_w   = (const float*)d_in[3];
  const int* knn_row  = (const int*)d_in[4];
  const int* knn_col  = (const int*)d_in[5];
  const float* knn_w  = (const float*)d_in[6];
  const float* W_dm1  = (const float*)d_in[7];
  const float* b_dm1  = (const float*)d_in[8];
  const float* g_dm   = (const float*)d_in[9];
  const float* be_dm  = (const float*)d_in[10];
  const float* m_dm   = (const float*)d_in[11];
  const float* v_dm   = (const float*)d_in[12];
  const float* W_dm2  = (const float*)d_in[13];
  const float* b_dm2  = (const float*)d_in[14];
  const float* W_knn1 = (const float*)d_in[15];
  const float* b_knn1 = (const float*)d_in[16];
  const float* g_knn  = (const float*)d_in[17];
  const float* be_knn = (const float*)d_in[18];
  const float* m_knn  = (const float*)d_in[19];
  const float* v_knn  = (const float*)d_in[20];
  const float* W_knn2 = (const float*)d_in[21];
  const float* b_knn2 = (const float*)d_in[22];
  float* out = (float*)d_out;

  const int E = in_sizes[1];

  // ---- workspace layout: identical footprint to the proven round-2 layout (~51 MB) ----
  float* wbase = (float*)d_ws;
  size_t o = 0;
  auto alloc = [&](size_t n) { float* p = wbase + o; o += (n + 3) & ~size_t(3); return p; };
  int* cnt_dm   = (int*)alloc(NN);
  int* cnt_knn  = (int*)alloc(NN);
  int* rp_dm    = (int*)alloc(NN + 1);
  int* off_dm   = (int*)alloc(NN);
  int* rp_knn   = (int*)alloc(NN + 1);
  int* off_knn  = (int*)alloc(NN);
  int* cs_dm    = (int*)alloc(E);
  float* wv_dm  = alloc(E);
  int* cs_knn   = (int*)alloc(E);
  float* wv_knn = alloc(E);
  float* Yb  = alloc((size_t)NN * 384);
  float* T1  = alloc((size_t)NN * HH);
  float* T2c = alloc((size_t)NN * HH);
  float* Hb  = T1;                 // reuse (proven in round 2)
  float* Pb  = T2c;                // reuse
  float* T15 = Yb;                 // reuse
  _Float16* WT = (_Float16*)T2c;   // WT[384*2016] fp16 = 1.55 MB < 8.4 MB; consumed by gemm
                                   // before spmm128 #2 writes T2c (stream-ordered)

  hipMemsetAsync(cnt_dm, 0, 2 * NN * sizeof(int), stream);
  int nb2e = (2 * E + 255) / 256;
  hist_kernel<<<nb2e, 256, 0, stream>>>(dm_row, knn_row, cnt_dm, cnt_knn, E);
  scan_kernel<<<2, 256, 0, stream>>>(cnt_dm, rp_dm, off_dm, cnt_knn, rp_knn, off_knn);
  scatter_kernel<<<nb2e, 256, 0, stream>>>(dm_row, dm_col, dm_w, knn_row, knn_col, knn_w,
                                           off_dm, cs_dm, wv_dm, off_knn, cs_knn, wv_knn, E);

  for (int b = 0; b < 2; ++b) {
    const int* rp   = b ? rp_knn : rp_dm;
    const int* cs   = b ? cs_knn : cs_dm;
    const float* wv = b ? wv_knn : wv_dm;
    const float* W1 = b ? W_knn1 : W_dm1;
    const float* W2 = b ? W_knn2 : W_dm2;
    const float* b1 = b ? b_knn1 : b_dm1;
    const float* b2 = b ? b_knn2 : b_dm2;
    const float* g  = b ? g_knn : g_dm;
    const float* be = b ? be_knn : be_dm;
    const float* mm = b ? m_knn : m_dm;
    const float* vv = b ? v_knn : v_dm;

    // WT = transpose(W1) in fp16, zero-padded to K=2016
    build_wt<<<(384 * KP + 255) / 256, 256, 0, stream>>>(W1, WT);
    // Yb = [x@W0 | x@W1 | x@W2] via fp16 MFMA
    gemm1_mfma<<<dim3(3, NN / 128), 256, 0, stream>>>(x, WT, Yb);
    // T1 = A*(x@W2) + (x@W1)
    spmm128_kernel<<<NN / 4, 256, 0, stream>>>(rp, cs, wv, Yb + 256, 384, Yb + 128, 384, T1);
    // T2 = A*T1   (overwrites WT region -- WT already consumed)
    spmm128_kernel<<<NN / 4, 256, 0, stream>>>(rp, cs, wv, T1, HH, nullptr, 0, T2c);
    // H = relu(bn(Y0 + T2 + b1))
    bnrelu_kernel<<<(NN * HH) / 256, 256, 0, stream>>>(Yb, 384, T2c, b1, g, be, mm, vv, Hb);
    // P = H @ [V0|V1|V2]
    gemm2_kernel<<<NN / 16, 256, 0, stream>>>(Hb, W2, Pb);
    // T15 = A*P2 + P1
    spmm15_kernel<<<NN / 16, 256, 0, stream>>>(rp, cs, wv, Pb, 45, 30, Pb, 45, 15, nullptr, T15, 15, 0);
    // out (=/+=) A*T15 + P0 + b2
    spmm15_kernel<<<NN / 16, 256, 0, stream>>>(rp, cs, wv, T15, 15, 0, Pb, 45, 0, b2, out, 15, b);
  }
}

// Round 9
// 788.085 us; speedup vs baseline: 1.6677x; 1.0641x over previous
//
#include <hip/hip_runtime.h>

#define NN 16384
#define FF 2000
#define HH 128
#define LL 15
#define KP 2016   // 63 * 32, zero-padded K
constexpr float BN_EPS = 1e-3f;

typedef _Float16 half8 __attribute__((ext_vector_type(8)));
typedef __fp16 fp16x2 __attribute__((ext_vector_type(2)));
typedef float f32x4 __attribute__((ext_vector_type(4)));

// ---------------- CSR build: histogram ----------------
__global__ void hist_kernel(const int* __restrict__ dm_row, const int* __restrict__ knn_row,
                            int* __restrict__ cnt_dm, int* __restrict__ cnt_knn, int E) {
  int i = blockIdx.x * 256 + threadIdx.x;
  if (i < E) atomicAdd(&cnt_dm[dm_row[i]], 1);
  else if (i - E < E) atomicAdd(&cnt_knn[knn_row[i - E]], 1);
}

// ---------------- CSR build: exclusive scan ----------------
__global__ void scan_kernel(const int* __restrict__ cnt0, int* __restrict__ rp0, int* __restrict__ off0,
                            const int* __restrict__ cnt1, int* __restrict__ rp1, int* __restrict__ off1) {
  const int* cnt = blockIdx.x ? cnt1 : cnt0;
  int* rp  = blockIdx.x ? rp1 : rp0;
  int* off = blockIdx.x ? off1 : off0;
  __shared__ int part[256];
  __shared__ int totsh;
  int t = threadIdx.x;
  int s = 0;
  for (int i = 0; i < 64; ++i) s += cnt[t * 64 + i];
  part[t] = s;
  __syncthreads();
  if (t == 0) {
    int run = 0;
    for (int i = 0; i < 256; ++i) { int c = part[i]; part[i] = run; run += c; }
    totsh = run;
  }
  __syncthreads();
  int base = part[t];
  for (int i = 0; i < 64; ++i) {
    int idx = t * 64 + i;
    rp[idx] = base;
    off[idx] = base;
    base += cnt[idx];
  }
  if (t == 0) rp[NN] = totsh;
}

// ---------------- CSR build: scatter ----------------
__global__ void scatter_kernel(const int* __restrict__ dm_row, const int* __restrict__ dm_col, const float* __restrict__ dm_w,
                               const int* __restrict__ knn_row, const int* __restrict__ knn_col, const float* __restrict__ knn_w,
                               int* __restrict__ off_dm, int* __restrict__ cs_dm, float* __restrict__ wv_dm,
                               int* __restrict__ off_knn, int* __restrict__ cs_knn, float* __restrict__ wv_knn, int E) {
  int i = blockIdx.x * 256 + threadIdx.x;
  if (i < E) {
    int r = dm_row[i];
    int p = atomicAdd(&off_dm[r], 1);
    cs_dm[p] = dm_col[i];
    wv_dm[p] = dm_w[i];
  } else if (i - E < E) {
    int j = i - E;
    int r = knn_row[j];
    int p = atomicAdd(&off_knn[r], 1);
    cs_knn[p] = knn_col[j];
    wv_knn[p] = knn_w[j];
  }
}

// ---------------- WT build (coalesced, LDS transpose) ----------------
// WT[j][k] fp16, j = p*128 + h in [0,384), k in [0,2016); zero-pad k >= 2000.
// grid: 3 parts x 126 k-tiles of 16; block 256.
__global__ void build_wt(const float* __restrict__ W1, _Float16* __restrict__ WT) {
  __shared__ _Float16 tile[128][18];   // [h][k-within-tile], padded
  int b = blockIdx.x;
  int p = b / 126, kt = b % 126;
  int t = threadIdx.x;
  // read phase: k = t>>4 (0..15), h0 = (t&15)*8 ; 8 contiguous floats
  int k = t >> 4, h0 = (t & 15) * 8;
  int kg = kt * 16 + k;
  float4 v0 = make_float4(0.f, 0.f, 0.f, 0.f), v1 = v0;
  if (kg < FF) {
    const float* src = W1 + ((size_t)p * FF + kg) * HH + h0;
    v0 = *(const float4*)src;
    v1 = *(const float4*)(src + 4);
  }
  tile[h0 + 0][k] = (_Float16)v0.x;
  tile[h0 + 1][k] = (_Float16)v0.y;
  tile[h0 + 2][k] = (_Float16)v0.z;
  tile[h0 + 3][k] = (_Float16)v0.w;
  tile[h0 + 4][k] = (_Float16)v1.x;
  tile[h0 + 5][k] = (_Float16)v1.y;
  tile[h0 + 6][k] = (_Float16)v1.z;
  tile[h0 + 7][k] = (_Float16)v1.w;
  __syncthreads();
  // write phase: j = t>>1 (0..127), ko = (t&1)*8 ; 8 contiguous halfs = 16B
  int j = t >> 1, ko = (t & 1) * 8;
  union { _Float16 h[8]; uint4 u; } o;
#pragma unroll
  for (int q = 0; q < 8; ++q) o.h[q] = tile[j][ko + q];
  *(uint4*)(WT + ((size_t)p * 128 + j) * KP + kt * 16 + ko) = o.u;
}

// ---------------- GEMM1 MFMA: Yb[16384 x 384] = X @ W (fp16 in, fp32 acc) ----------------
// 64x128 tile, 768 blocks (3/CU), 3-deep reg prefetch, 80B-padded LDS rows.
__global__ __launch_bounds__(256, 3) void gemm1_mfma(const float* __restrict__ X,
                                                     const _Float16* __restrict__ WT,
                                                     float* __restrict__ Yb) {
  // LDS: [buf][A 64x40u | B 128x40u]  (row stride 80B)
  __shared__ char lds[2 * 15360];
#define ASB(c) (lds + (c) * 15360)
#define BSB(c) (lds + (c) * 15360 + 5120)

  const int t = threadIdx.x;
  // XCD swizzle: 768 = 8*96, bijective; 3 n-siblings of an m-tile share an XCD
  int bid = blockIdx.x;
  int wg = (bid & 7) * 96 + (bid >> 3);
  const int mb = wg / 3, nb = wg - 3 * mb;
  const int m0 = mb * 64, n0 = nb * 128;

  const int wid = t >> 6, lane = t & 63;
  const int wr = wid >> 1, wc = wid & 1;       // wave tile: 32 rows x 64 cols
  const int l15 = lane & 15, lk = lane >> 4;

  // staging: A: thread -> row t>>2, k-seg (t&3)*8 floats (32B); B: row t>>1, k-seg (t&1)*16 halfs (32B)
  const int srA = t >> 2, skA = (t & 3) * 8;
  const int srB = t >> 1, skB = (t & 1) * 16;
  const int awo = srA * 80 + (t & 3) * 16;     // A LDS write byte offset (16B)
  const int bwo = srB * 80 + (t & 1) * 32;     // B LDS write byte offset (2x16B)

  const float* Xp = X + (size_t)(m0 + srA) * FF + skA;
  const _Float16* Wp = WT + (size_t)(n0 + srB) * KP + skB;

  // fragment read byte-offsets (within a buffer)
  int a_r[2], b_r[4];
#pragma unroll
  for (int i = 0; i < 2; ++i) a_r[i] = (wr * 32 + i * 16 + l15) * 80 + lk * 16;
#pragma unroll
  for (int j = 0; j < 4; ++j) b_r[j] = (wc * 64 + j * 16 + l15) * 80 + lk * 16;

  struct Sreg { float4 a0, a1; uint4 b0, b1; };
  Sreg S0, S1, S2;

  auto LOADS = [&](Sreg& S, int T) {
    int k0 = T * 32;
    int k0c = (k0 < 1984) ? k0 : 1984;
    bool aval = (k0 + skA) < FF;               // 8-aligned segment fully valid or pad (2000%8==0)
    const float* Xq = Xp + (aval ? k0c : 0);   // clamp address when invalid (stay in-bounds)
    float4 fz = make_float4(0.f, 0.f, 0.f, 0.f);
    S.a0 = aval ? *(const float4*)Xq : fz;
    S.a1 = aval ? *(const float4*)(Xq + 4) : fz;
    const _Float16* Wq = Wp + k0c;             // WT padded to 2016: always in-bounds
    S.b0 = *(const uint4*)Wq;
    S.b1 = *(const uint4*)(Wq + 8);
  };

  auto STAGE = [&](const Sreg& S, char* ab, char* bb) {
    fp16x2 h0 = __builtin_amdgcn_cvt_pkrtz(S.a0.x, S.a0.y);
    fp16x2 h1 = __builtin_amdgcn_cvt_pkrtz(S.a0.z, S.a0.w);
    fp16x2 h2 = __builtin_amdgcn_cvt_pkrtz(S.a1.x, S.a1.y);
    fp16x2 h3 = __builtin_amdgcn_cvt_pkrtz(S.a1.z, S.a1.w);
    *(uint4*)(ab + awo) = make_uint4(__builtin_bit_cast(unsigned int, h0),
                                     __builtin_bit_cast(unsigned int, h1),
                                     __builtin_bit_cast(unsigned int, h2),
                                     __builtin_bit_cast(unsigned int, h3));
    *(uint4*)(bb + bwo) = S.b0;
    *(uint4*)(bb + bwo + 16) = S.b1;
  };

  f32x4 acc[2][4];
#pragma unroll
  for (int i = 0; i < 2; ++i)
#pragma unroll
    for (int j = 0; j < 4; ++j) acc[i][j] = (f32x4)0.f;

  // prologue: tiles 0,1,2 -> S0,S1,S2 ; stage tile0 -> buf0
  LOADS(S0, 0);
  LOADS(S1, 1);
  LOADS(S2, 2);
  STAGE(S0, ASB(0), BSB(0));

  int cur = 0;
#define GI(T, SLD, SST)                                                         \
  do {                                                                          \
    __syncthreads();                                                            \
    char* ca = ASB(cur); char* cb = BSB(cur);                                   \
    half8 af[2], bf[4];                                                         \
    _Pragma("unroll") for (int i = 0; i < 2; ++i)                               \
        af[i] = *(const half8*)(ca + a_r[i]);                                   \
    _Pragma("unroll") for (int j = 0; j < 4; ++j)                               \
        bf[j] = *(const half8*)(cb + b_r[j]);                                   \
    LOADS(SLD, (T) + 3);                                                        \
    _Pragma("unroll") for (int i = 0; i < 2; ++i)                               \
      _Pragma("unroll") for (int j = 0; j < 4; ++j)                             \
        acc[i][j] = __builtin_amdgcn_mfma_f32_16x16x32_f16(af[i], bf[j],        \
                                                           acc[i][j], 0, 0, 0);\
    STAGE(SST, ASB(cur ^ 1), BSB(cur ^ 1));                                     \
    cur ^= 1;                                                                   \
  } while (0)

  // 63 iterations = 21 triples; iter T consumes tile T, stages tile T+1,
  // loads tile T+3 into the slot freed at T-1. Final iter stages a dead tile
  // (loads clamped in-bounds; never read).
  for (int tp = 0; tp < 21; ++tp) {
    GI(3 * tp + 0, S0, S1);
    GI(3 * tp + 1, S1, S2);
    GI(3 * tp + 2, S2, S0);
  }
#undef GI

  // epilogue: C/D layout col=lane&15, row=(lane>>4)*4+reg
#pragma unroll
  for (int i = 0; i < 2; ++i) {
#pragma unroll
    for (int j = 0; j < 4; ++j) {
      int row = m0 + wr * 32 + i * 16 + lk * 4;
      int col = n0 + wc * 64 + j * 16 + l15;
#pragma unroll
      for (int r = 0; r < 4; ++r)
        Yb[(size_t)(row + r) * 384 + col] = acc[i][j][r];
    }
  }
#undef ASB
#undef BSB
}

// ---------------- spmm width 128 ----------------
__global__ void spmm128_kernel(const int* __restrict__ rp, const int* __restrict__ cs, const float* __restrict__ wv,
                               const float* __restrict__ src, int sstr,
                               const float* __restrict__ addv, int astr,
                               float* __restrict__ dst) {
  int row = blockIdx.x * 4 + (threadIdx.x >> 6);
  int lane = threadIdx.x & 63;
  int e0 = rp[row], e1 = rp[row + 1];
  float ax = 0.f, ay = 0.f;
  int e = e0;
  for (; e + 3 < e1; e += 4) {
    int c0 = cs[e], c1 = cs[e + 1], c2 = cs[e + 2], c3 = cs[e + 3];
    float w0 = wv[e], w1 = wv[e + 1], w2 = wv[e + 2], w3 = wv[e + 3];
    float2 v0 = *(const float2*)(src + (size_t)c0 * sstr + 2 * lane);
    float2 v1 = *(const float2*)(src + (size_t)c1 * sstr + 2 * lane);
    float2 v2 = *(const float2*)(src + (size_t)c2 * sstr + 2 * lane);
    float2 v3 = *(const float2*)(src + (size_t)c3 * sstr + 2 * lane);
    ax = fmaf(w0, v0.x, ax); ay = fmaf(w0, v0.y, ay);
    ax = fmaf(w1, v1.x, ax); ay = fmaf(w1, v1.y, ay);
    ax = fmaf(w2, v2.x, ax); ay = fmaf(w2, v2.y, ay);
    ax = fmaf(w3, v3.x, ax); ay = fmaf(w3, v3.y, ay);
  }
  for (; e < e1; ++e) {
    int c = cs[e];
    float wgt = wv[e];
    float2 v = *(const float2*)(src + (size_t)c * sstr + 2 * lane);
    ax = fmaf(wgt, v.x, ax);
    ay = fmaf(wgt, v.y, ay);
  }
  if (addv) {
    ax += addv[(size_t)row * astr + 2 * lane];
    ay += addv[(size_t)row * astr + 2 * lane + 1];
  }
  *(float2*)(dst + (size_t)row * HH + 2 * lane) = make_float2(ax, ay);
}

// ---------------- BN + ReLU ----------------
__global__ void bnrelu_kernel(const float* __restrict__ Y0, int ystr, const float* __restrict__ T2,
                              const float* __restrict__ b1, const float* __restrict__ g,
                              const float* __restrict__ be, const float* __restrict__ m,
                              const float* __restrict__ v, float* __restrict__ H) {
  int i = blockIdx.x * 256 + threadIdx.x;
  int row = i >> 7, h = i & 127;
  float tv = Y0[(size_t)row * ystr + h] + T2[i] + b1[h];
  float yv = g[h] * (tv - m[h]) * rsqrtf(v[h] + BN_EPS) + be[h];
  H[i] = fmaxf(yv, 0.f);
}

// ---------------- GEMM2: P[N x 45] = H[N x 128] @ [V0|V1|V2] ----------------
__global__ void gemm2_kernel(const float* __restrict__ H, const float* __restrict__ W2,
                             float* __restrict__ P) {
  __shared__ float V[128 * 48];
  int t = threadIdx.x;
  for (int idx = t; idx < 128 * 48; idx += 256) {
    int k = idx / 48, j = idx % 48;
    float val = 0.f;
    if (j < 45) {
      int p = j / 15, l = j % 15;
      val = W2[(size_t)(p * 128 + k) * 15 + l];
    }
    V[idx] = val;
  }
  __syncthreads();
  int rq = t >> 4, l = t & 15;
  int row = blockIdx.x * 16 + rq;
  float a0 = 0.f, a1 = 0.f, a2 = 0.f;
  const float* hrow = H + (size_t)row * 128;
  for (int k = 0; k < 128; ++k) {
    float hv = hrow[k];
    a0 = fmaf(hv, V[k * 48 + l], a0);
    a1 = fmaf(hv, V[k * 48 + 16 + l], a1);
    a2 = fmaf(hv, V[k * 48 + 32 + l], a2);
  }
  float* pr = P + (size_t)row * 45;
  pr[l] = a0;
  pr[16 + l] = a1;
  if (l < 13) pr[32 + l] = a2;
}

// ---------------- spmm width 15 (16 lanes per row) ----------------
__global__ void spmm15_kernel(const int* __restrict__ rp, const int* __restrict__ cs, const float* __restrict__ wv,
                              const float* __restrict__ src, int sstr, int soff,
                              const float* __restrict__ addv, int astr, int aoff,
                              const float* __restrict__ bias,
                              float* __restrict__ dst, int dstr, int accum) {
  int t = threadIdx.x;
  int rq = t >> 4, f = t & 15;
  int row = blockIdx.x * 16 + rq;
  int e0 = rp[row], e1 = rp[row + 1];
  bool valid = f < 15;
  int ff = valid ? f : 0;
  float acc = 0.f;
  for (int e = e0; e < e1; ++e) {
    int c = cs[e];
    float wgt = wv[e];
    acc = fmaf(wgt, src[(size_t)c * sstr + soff + ff], acc);
  }
  if (addv) acc += addv[(size_t)row * astr + aoff + ff];
  if (bias) acc += bias[ff];
  if (valid) {
    float* d = dst + (size_t)row * dstr + f;
    if (accum) *d += acc;
    else *d = acc;
  }
}

extern "C" void kernel_launch(void* const* d_in, const int* in_sizes, int n_in,
                              void* d_out, int out_size, void* d_ws, size_t ws_size,
                              hipStream_t stream) {
  const float* x      = (const float*)d_in[0];
  const int* dm_row   = (const int*)d_in[1];
  const int* dm_col   = (const int*)d_in[2];
  const float* dm_w   = (const float*)d_in[3];
  const int* knn_row  = (const int*)d_in[4];
  const int* knn_col  = (const int*)d_in[5];
  const float* knn_w  = (const float*)d_in[6];
  const float* W_dm1  = (const float*)d_in[7];
  const float* b_dm1  = (const float*)d_in[8];
  const float* g_dm   = (const float*)d_in[9];
  const float* be_dm  = (const float*)d_in[10];
  const float* m_dm   = (const float*)d_in[11];
  const float* v_dm   = (const float*)d_in[12];
  const float* W_dm2  = (const float*)d_in[13];
  const float* b_dm2  = (const float*)d_in[14];
  const float* W_knn1 = (const float*)d_in[15];
  const float* b_knn1 = (const float*)d_in[16];
  const float* g_knn  = (const float*)d_in[17];
  const float* be_knn = (const float*)d_in[18];
  const float* m_knn  = (const float*)d_in[19];
  const float* v_knn  = (const float*)d_in[20];
  const float* W_knn2 = (const float*)d_in[21];
  const float* b_knn2 = (const float*)d_in[22];
  float* out = (float*)d_out;

  const int E = in_sizes[1];

  // ---- workspace layout: identical footprint to the proven round-2 layout (~51 MB) ----
  float* wbase = (float*)d_ws;
  size_t o = 0;
  auto alloc = [&](size_t n) { float* p = wbase + o; o += (n + 3) & ~size_t(3); return p; };
  int* cnt_dm   = (int*)alloc(NN);
  int* cnt_knn  = (int*)alloc(NN);
  int* rp_dm    = (int*)alloc(NN + 1);
  int* off_dm   = (int*)alloc(NN);
  int* rp_knn   = (int*)alloc(NN + 1);
  int* off_knn  = (int*)alloc(NN);
  int* cs_dm    = (int*)alloc(E);
  float* wv_dm  = alloc(E);
  int* cs_knn   = (int*)alloc(E);
  float* wv_knn = alloc(E);
  float* Yb  = alloc((size_t)NN * 384);
  float* T1  = alloc((size_t)NN * HH);
  float* T2c = alloc((size_t)NN * HH);
  float* Hb  = T1;                 // reuse (proven)
  float* Pb  = T2c;                // reuse
  float* T15 = Yb;                 // reuse
  _Float16* WT = (_Float16*)T2c;   // WT[384*2016] fp16 = 1.55 MB; consumed by gemm
                                   // before spmm128 #2 writes T2c (stream-ordered)

  hipMemsetAsync(cnt_dm, 0, 2 * NN * sizeof(int), stream);
  int nb2e = (2 * E + 255) / 256;
  hist_kernel<<<nb2e, 256, 0, stream>>>(dm_row, knn_row, cnt_dm, cnt_knn, E);
  scan_kernel<<<2, 256, 0, stream>>>(cnt_dm, rp_dm, off_dm, cnt_knn, rp_knn, off_knn);
  scatter_kernel<<<nb2e, 256, 0, stream>>>(dm_row, dm_col, dm_w, knn_row, knn_col, knn_w,
                                           off_dm, cs_dm, wv_dm, off_knn, cs_knn, wv_knn, E);

  for (int b = 0; b < 2; ++b) {
    const int* rp   = b ? rp_knn : rp_dm;
    const int* cs   = b ? cs_knn : cs_dm;
    const float* wv = b ? wv_knn : wv_dm;
    const float* W1 = b ? W_knn1 : W_dm1;
    const float* W2 = b ? W_knn2 : W_dm2;
    const float* b1 = b ? b_knn1 : b_dm1;
    const float* b2 = b ? b_knn2 : b_dm2;
    const float* g  = b ? g_knn : g_dm;
    const float* be = b ? be_knn : be_dm;
    const float* mm = b ? m_knn : m_dm;
    const float* vv = b ? v_knn : v_dm;

    // WT = transpose(W1) in fp16, zero-padded to K=2016 (coalesced via LDS)
    build_wt<<<3 * 126, 256, 0, stream>>>(W1, WT);
    // Yb = [x@W0 | x@W1 | x@W2] via fp16 MFMA (64x128 tiles, 768 blocks)
    gemm1_mfma<<<768, 256, 0, stream>>>(x, WT, Yb);
    // T1 = A*(x@W2) + (x@W1)
    spmm128_kernel<<<NN / 4, 256, 0, stream>>>(rp, cs, wv, Yb + 256, 384, Yb + 128, 384, T1);
    // T2 = A*T1   (overwrites WT region -- WT already consumed)
    spmm128_kernel<<<NN / 4, 256, 0, stream>>>(rp, cs, wv, T1, HH, nullptr, 0, T2c);
    // H = relu(bn(Y0 + T2 + b1))
    bnrelu_kernel<<<(NN * HH) / 256, 256, 0, stream>>>(Yb, 384, T2c, b1, g, be, mm, vv, Hb);
    // P = H @ [V0|V1|V2]
    gemm2_kernel<<<NN / 16, 256, 0, stream>>>(Hb, W2, Pb);
    // T15 = A*P2 + P1
    spmm15_kernel<<<NN / 16, 256, 0, stream>>>(rp, cs, wv, Pb, 45, 30, Pb, 45, 15, nullptr, T15, 15, 0);
    // out (=/+=) A*T15 + P0 + b2
    spmm15_kernel<<<NN / 16, 256, 0, stream>>>(rp, cs, wv, T15, 15, 0, Pb, 45, 0, b2, out, 15, b);
  }
}